// Round 8
// baseline (337.500 us; speedup 1.0000x reference)
//
#include <hip/hip_runtime.h>

#define NB 16
#define NT 4096
#define ND 512
#define NLEV 12
#define TILE 32          // j's per block
#define WROWS 40         // staged rows per block: TILE + 8 band  (40*2048B = 80KB)

typedef float f4v __attribute__((ext_vector_type(4)));

// ---------- exact decision path (verified rounds 2-7): f32 diffs, exact f64 sum,
// ---------- round once to f32, compare vs 1024 (== 32^2, monotone w/ sqrtf>32).
__device__ __forceinline__ bool decide_exact(const float* __restrict__ base, int row,
                                             int lane, float4 r0, float4 r1) {
    const float4* fp = (const float4*)(base + (size_t)row * ND);
    float4 y0 = fp[lane];
    float4 y1 = fp[lane + 64];
    float d;
    double sd;
    d = r0.x - y0.x; sd  = (double)d * d;
    d = r0.y - y0.y; sd += (double)d * d;
    d = r0.z - y0.z; sd += (double)d * d;
    d = r0.w - y0.w; sd += (double)d * d;
    d = r1.x - y1.x; sd += (double)d * d;
    d = r1.y - y1.y; sd += (double)d * d;
    d = r1.z - y1.z; sd += (double)d * d;
    d = r1.w - y1.w; sd += (double)d * d;
    #pragma unroll
    for (int off = 32; off >= 1; off >>= 1) sd += __shfl_xor(sd, off, 64);
    return ((float)sd > 1024.0f);
}

// ---------------- Kernel A v8: tile-in-LDS screening ------------------------------
// Block stages rows [j0, j0+WROWS) in LDS; 4 waves screen 32 j's from LDS.
// Screen math identical to verified r5 core (16-lane groups, 4 probes/batch,
// f32 fmaf chains + 4 shuffles, +-0.25 band -> exact-f64 global path).
__global__ __launch_bounds__(256) void kA_next(const float* __restrict__ in,
                                               int* __restrict__ nxt) {
    __shared__ float lds[WROWS * ND];    // 80 KB -> 2 blocks/CU
    int tid  = threadIdx.x;
    int j0g  = blockIdx.x * TILE;        // global j index of tile start (b,jl fused)
    int b    = j0g >> 12;
    int j0   = j0g & (NT - 1);           // local tile start within sequence
    int win  = min(WROWS, NT - j0);      // staged rows: j0 .. j0+win-1

    const float* base = in + (size_t)b * NT * ND;

    // ---- phase 1: bulk coalesced stage (one pass, high MLP) ----
    {
        const float4* g4 = (const float4*)(base + (size_t)j0 * ND);
        float4* l4w = (float4*)lds;
        int elems4 = win * (ND / 4);
        for (int idx = tid; idx < elems4; idx += 256) l4w[idx] = g4[idx];
    }
    __syncthreads();

    // ---- phase 2: per-wave screening from LDS ----
    int w    = tid >> 6;
    int lane = tid & 63;
    int g    = lane >> 4;    // probe group 0..3
    int q    = lane & 15;    // lane within group
    const float4* l4 = (const float4*)lds;

    for (int t = 0; t < 8; ++t) {
        int jj = w + 4 * t;              // row of this j within window (0..31)
        int jl = j0 + jj;                // local j within sequence
        const float4* jrowg = (const float4*)(base + (size_t)jl * ND);

        float4 rep[8];
        #pragma unroll
        for (int k = 0; k < 8; ++k) rep[k] = l4[jj * (ND / 4) + q + 16 * k];

        int found = -1;
        for (int br = jj + 1; br < win && found < 0; br += 4) {
            int rr = br + g;
            bool valid = rr < win;
            int rc = valid ? rr : win - 1;
            float s = 0.f;
            #pragma unroll
            for (int k = 0; k < 8; ++k) {
                float4 x = l4[rc * (ND / 4) + q + 16 * k];
                float d;
                d = rep[k].x - x.x; s = fmaf(d, d, s);
                d = rep[k].y - x.y; s = fmaf(d, d, s);
                d = rep[k].z - x.z; s = fmaf(d, d, s);
                d = rep[k].w - x.w; s = fmaf(d, d, s);
            }
            s += __shfl_xor(s, 1, 64);
            s += __shfl_xor(s, 2, 64);
            s += __shfl_xor(s, 4, 64);
            s += __shfl_xor(s, 8, 64);

            unsigned long long ym = __ballot(q == 0 && valid && s > 1024.25f);
            unsigned long long am = __ballot(q == 0 && valid && s > 1023.75f && s <= 1024.25f);
            unsigned vy = (unsigned)((ym & 1ull) | ((ym >> 15) & 2ull) |
                                     ((ym >> 30) & 4ull) | ((ym >> 45) & 8ull));
            unsigned va = (unsigned)((am & 1ull) | ((am >> 15) & 2ull) |
                                     ((am >> 30) & 4ull) | ((am >> 45) & 8ull));
            for (;;) {   // wave-uniform resolve in ascending probe order
                int gy = vy ? (__ffs(vy) - 1) : 4;
                int ga = va ? (__ffs(va) - 1) : 4;
                if (ga < gy) {
                    float4 r0 = jrowg[lane];          // rare path; global reload
                    float4 r1 = jrowg[lane + 64];
                    if (decide_exact(base, j0 + br + ga, lane, r0, r1)) {
                        found = j0 + br + ga; break;
                    }
                    va &= va - 1;
                } else {
                    if (gy < 4) found = j0 + br + gy;
                    break;
                }
            }
        }

        int result;
        if (found >= 0) {
            result = found;
        } else if (j0 + win >= NT) {
            result = NT;                 // window reached sequence end: no exceed
        } else {
            // ---- rare fallback (~0.8% of j): verified r5 global probe loop ----
            result = NT;
            int i = j0 + win;
            while (i < NT) {
                int row = i + g;
                bool valid = row < NT;
                int rc = valid ? row : NT - 1;
                const float4* pr = (const float4*)(base + (size_t)rc * ND);
                float s = 0.f;
                #pragma unroll
                for (int k = 0; k < 8; ++k) {
                    float4 x = pr[q + 16 * k];
                    float d;
                    d = rep[k].x - x.x; s = fmaf(d, d, s);
                    d = rep[k].y - x.y; s = fmaf(d, d, s);
                    d = rep[k].z - x.z; s = fmaf(d, d, s);
                    d = rep[k].w - x.w; s = fmaf(d, d, s);
                }
                s += __shfl_xor(s, 1, 64);
                s += __shfl_xor(s, 2, 64);
                s += __shfl_xor(s, 4, 64);
                s += __shfl_xor(s, 8, 64);
                unsigned long long ym = __ballot(q == 0 && valid && s > 1024.25f);
                unsigned long long am = __ballot(q == 0 && valid && s > 1023.75f && s <= 1024.25f);
                unsigned vy = (unsigned)((ym & 1ull) | ((ym >> 15) & 2ull) |
                                         ((ym >> 30) & 4ull) | ((ym >> 45) & 8ull));
                unsigned va = (unsigned)((am & 1ull) | ((am >> 15) & 2ull) |
                                         ((am >> 30) & 4ull) | ((am >> 45) & 8ull));
                int f2 = -1;
                for (;;) {
                    int gy = vy ? (__ffs(vy) - 1) : 4;
                    int ga = va ? (__ffs(va) - 1) : 4;
                    if (ga < gy) {
                        float4 r0 = jrowg[lane];
                        float4 r1 = jrowg[lane + 64];
                        if (decide_exact(base, i + ga, lane, r0, r1)) { f2 = i + ga; break; }
                        va &= va - 1;
                    } else {
                        if (gy < 4) f2 = i + gy;
                        break;
                    }
                }
                if (f2 >= 0) { result = f2; break; }
                i += 4;
            }
        }
        if (lane == 0) nxt[b * NT + jl] = result;
    }
}

// ---------------- kChain v2: doubling + per-bit-parallel closure (verified r7) -----
__global__ __launch_bounds__(1024) void kChain(const int* __restrict__ nxt,
                                               int* __restrict__ start,
                                               int* __restrict__ nseg,
                                               float* __restrict__ out_tail) {
    __shared__ unsigned short h[NT + 1];
    __shared__ unsigned short h2[NT + 1];
    __shared__ unsigned reach[NT / 32];
    __shared__ unsigned pref[NT / 32];
    int b = blockIdx.x;
    int t = threadIdx.x;
    for (int j = t; j <= NT; j += 1024)
        h[j] = (j < NT) ? (unsigned short)nxt[b * NT + j] : (unsigned short)NT;
    for (int w = t; w < NT / 32; w += 1024) reach[w] = 0;
    __syncthreads();
    if (t == 0) reach[0] = 1u;
    __syncthreads();
    for (int k = 0; k < NLEV; ++k) {
        #pragma unroll
        for (int j = t; j < NT; j += 1024) {
            if (reach[j >> 5] & (1u << (j & 31))) {
                int d = h[j];
                if (d < NT) atomicOr(&reach[d >> 5], 1u << (d & 31));
            }
        }
        __syncthreads();
        for (int j = t; j <= NT; j += 1024) h2[j] = h[h[j]];
        __syncthreads();
        for (int j = t; j <= NT; j += 1024) h[j] = h2[j];
        __syncthreads();
    }
    if (t < NT / 32) pref[t] = __popc(reach[t]);
    __syncthreads();
    for (int off = 1; off < NT / 32; off <<= 1) {
        unsigned v = 0;
        if (t < NT / 32 && t >= off) v = pref[t - off];
        __syncthreads();
        if (t < NT / 32) pref[t] += v;
        __syncthreads();
    }
    int n = pref[NT / 32 - 1];
    for (int j = t; j < NT; j += 1024) {
        unsigned w = reach[j >> 5];
        if (w & (1u << (j & 31))) {
            int r = (int)(pref[j >> 5] - __popc(w) + __popc(w & ((1u << (j & 31)) - 1)));
            start[b * NT + r] = j;
        }
    }
    if (t == 0) { nseg[b] = n; out_tail[b] = (float)n; }
}

// ---------------- Kernel D: means + zeros, wave per row, nt stores (verified) ------
__global__ __launch_bounds__(256) void kD_means(const float* __restrict__ in,
                                                const int* __restrict__ nxt,
                                                const int* __restrict__ start,
                                                const int* __restrict__ nseg,
                                                float* __restrict__ out) {
    int wave = blockIdx.x * 4 + (threadIdx.x >> 6);   // 0..65535 = (b, r)
    int lane = threadIdx.x & 63;
    int b = wave >> 12;
    int r = wave & (NT - 1);
    float4 acc0 = make_float4(0.f, 0.f, 0.f, 0.f);
    float4 acc1 = make_float4(0.f, 0.f, 0.f, 0.f);
    int n = nseg[b];
    if (r < n) {
        int s = start[b * NT + r];
        int e = nxt[b * NT + s];
        const float4* base = (const float4*)(in + (size_t)(b * NT + s) * ND);
        int cnt = e - s;
        int f = 0;
        for (; f + 2 <= cnt; f += 2) {
            float4 v0 = base[(size_t)f * (ND / 4) + lane];
            float4 v1 = base[(size_t)f * (ND / 4) + lane + 64];
            float4 w0 = base[(size_t)(f + 1) * (ND / 4) + lane];
            float4 w1 = base[(size_t)(f + 1) * (ND / 4) + lane + 64];
            acc0.x += v0.x + w0.x; acc0.y += v0.y + w0.y;
            acc0.z += v0.z + w0.z; acc0.w += v0.w + w0.w;
            acc1.x += v1.x + w1.x; acc1.y += v1.y + w1.y;
            acc1.z += v1.z + w1.z; acc1.w += v1.w + w1.w;
        }
        if (f < cnt) {
            float4 v0 = base[(size_t)f * (ND / 4) + lane];
            float4 v1 = base[(size_t)f * (ND / 4) + lane + 64];
            acc0.x += v0.x; acc0.y += v0.y; acc0.z += v0.z; acc0.w += v0.w;
            acc1.x += v1.x; acc1.y += v1.y; acc1.z += v1.z; acc1.w += v1.w;
        }
        float c = (float)cnt;
        acc0.x /= c; acc0.y /= c; acc0.z /= c; acc0.w /= c;
        acc1.x /= c; acc1.y /= c; acc1.z /= c; acc1.w /= c;
    }
    f4v* orow = (f4v*)(out + (size_t)(b * NT + r) * ND);
    f4v o0 = {acc0.x, acc0.y, acc0.z, acc0.w};
    f4v o1 = {acc1.x, acc1.y, acc1.z, acc1.w};
    __builtin_nontemporal_store(o0, &orow[lane]);
    __builtin_nontemporal_store(o1, &orow[lane + 64]);
}

extern "C" void kernel_launch(void* const* d_in, const int* in_sizes, int n_in,
                              void* d_out, int out_size, void* d_ws, size_t ws_size,
                              hipStream_t stream) {
    const float* in = (const float*)d_in[0];
    float* out = (float*)d_out;
    char* ws = (char*)d_ws;

    int* nxt   = (int*)(ws + 0);           // 256 KiB
    int* start = (int*)(ws + 262144);      // 256 KiB
    int* nseg  = (int*)(ws + 524288);      // 64 B

    kA_next <<<NB * NT / TILE, 256,  0, stream>>>(in, nxt);
    kChain  <<<NB,             1024, 0, stream>>>(nxt, start, nseg,
                                                  out + (size_t)NB * NT * ND);
    kD_means<<<16384,          256,  0, stream>>>(in, nxt, start, nseg, out);
}